// Round 20
// baseline (563.219 us; speedup 1.0000x reference)
//
#include <hip/hip_runtime.h>
#include <hip/hip_bf16.h>

#define T_ 32
#define B_ 16
#define I_ 512
#define H_ 512
#define OFF_ 441
#define NR_ 71           // I_ - OFF_
#define NC_ 2556         // NR_*(NR_+1)/2
#define G4_ (4*NC_)      // 10224
#define NCP_ 2560        // K padded
#define NPR_ 10240       // padded gate-permuted row count
#define NTIL_ 640        // NPR_/16

typedef __attribute__((ext_vector_type(8))) short bf16x8;
typedef __attribute__((ext_vector_type(4))) float f32x4;
typedef __attribute__((ext_vector_type(4))) int   i32x4;

__device__ __forceinline__ ushort bfc(float f) {
    __hip_bfloat16 h = __float2bfloat16(f);
    return *(ushort*)&h;
}
__device__ __forceinline__ float b2f(ushort u) {
    return __uint_as_float((uint)u << 16);
}
__device__ __forceinline__ float sigf(float x) { return 1.f / (1.f + expf(-x)); }

__global__ void k_zero(float* __restrict__ p, int n) {
    int i = blockIdx.x * 256 + threadIdx.x;
    if (i < n) p[i] = 0.f;
}

// x fp32 [512][512] -> bf16 MFMA-fragment layout Xq[mt][ks][lane][8]
__global__ void k_cvt_xq(const float* __restrict__ x, ushort* __restrict__ Xq) {
    int tid = blockIdx.x * 256 + threadIdx.x;    // 0..32767
    int mt = tid >> 10, rem = tid & 1023;
    int ks = rem >> 6, lane = rem & 63;
    int row = lane & 15, kq = lane >> 4;
    const float* src = x + ((size_t)(mt * 16 + row)) * I_ + ks * 32 + kq * 8;
    float4 v0 = *(const float4*)(src);
    float4 v1 = *(const float4*)(src + 4);
    union { bf16x8 v; ushort us[8]; } o;
    o.us[0] = bfc(v0.x); o.us[1] = bfc(v0.y); o.us[2] = bfc(v0.z); o.us[3] = bfc(v0.w);
    o.us[4] = bfc(v1.x); o.us[5] = bfc(v1.y); o.us[6] = bfc(v1.z); o.us[7] = bfc(v1.w);
    *(bf16x8*)(Xq + (size_t)tid * 8) = o.v;
}

// Wih[l] fp32 [G4][512] -> bf16 gate-permuted MFMA-fragment layout
__global__ void k_cvt_w512q(const float* __restrict__ W0, const float* __restrict__ W1,
                            ushort* __restrict__ dst) {
    const int l = blockIdx.z;
    const float* src = l ? W1 : W0;
    int tid = blockIdx.x * 256 + threadIdx.x;    // 0..655359 per layer
    int nt = tid >> 10, rem = tid & 1023;
    int ks = rem >> 6, lane = rem & 63;
    int row = lane & 15, kq = lane >> 4;
    int np = nt * 16 + row;
    int jc = np >> 2, q = np & 3;
    union { bf16x8 v; ushort us[8]; } o;
    if (jc < NC_) {
        const float* sp = src + ((size_t)q * NC_ + jc) * I_ + ks * 32 + kq * 8;
        float4 v0 = *(const float4*)(sp);
        float4 v1 = *(const float4*)(sp + 4);
        o.us[0] = bfc(v0.x); o.us[1] = bfc(v0.y); o.us[2] = bfc(v0.z); o.us[3] = bfc(v0.w);
        o.us[4] = bfc(v1.x); o.us[5] = bfc(v1.y); o.us[6] = bfc(v1.z); o.us[7] = bfc(v1.w);
    } else {
        #pragma unroll
        for (int e = 0; e < 8; ++e) o.us[e] = 0;
    }
    *(bf16x8*)(dst + ((size_t)l * NTIL_ * 1024 + tid) * 8) = o.v;
}

// Whh[l] fp32 [G4][2556] -> int8, K=64-interleaved i8-MFMA fragment layout.
__global__ __launch_bounds__(256) void k_cvt_whh_i8(const float* __restrict__ W0,
        const float* __restrict__ W1,
        signed char* __restrict__ dst, float* __restrict__ sW) {
    const int l = blockIdx.z;
    const float* src = l ? W1 : W0;
    const int np = blockIdx.x * 4 + (threadIdx.x >> 6);
    const int lane = threadIdx.x & 63;
    const int jc = np >> 2, q = np & 3;
    float w[40];
    float mx = 0.f;
    if (jc < NC_) {
        const float* row = src + ((size_t)q * NC_ + jc) * NC_;
        #pragma unroll
        for (int g = 0; g < 5; ++g) {
            int k0 = g * 512 + lane * 8;
            #pragma unroll
            for (int e = 0; e < 8; ++e) {
                int k = k0 + e;
                float v = (k < NC_) ? row[k] : 0.f;
                w[g * 8 + e] = v;
                mx = fmaxf(mx, fabsf(v));
            }
        }
    } else {
        #pragma unroll
        for (int i = 0; i < 40; ++i) w[i] = 0.f;
    }
    #pragma unroll
    for (int d = 1; d < 64; d <<= 1) mx = fmaxf(mx, __shfl_xor(mx, d));
    const float inv = (mx > 0.f) ? 127.f / mx : 0.f;
    const int nt = np >> 4, r = np & 15;
    signed char* obase = dst + (((size_t)l * NTIL_ + nt) * 40) * 1024;
    #pragma unroll
    for (int g = 0; g < 5; ++g) {
        int k0 = g * 512 + lane * 8;
        int ks = k0 >> 6, kgrp = (k0 >> 4) & 3, e = k0 & 15;   // e in {0,8}
        uint lo = 0, hi = 0;
        #pragma unroll
        for (int ee = 0; ee < 4; ++ee) {
            lo |= ((uint)(uchar)(signed char)(int)rintf(w[g * 8 + ee] * inv)) << (8 * ee);
            hi |= ((uint)(uchar)(signed char)(int)rintf(w[g * 8 + 4 + ee] * inv)) << (8 * ee);
        }
        *(uint2*)(obase + (size_t)ks * 1024 + (kgrp * 16 + r) * 16 + e) = make_uint2(lo, hi);
    }
    if (lane == 0) sW[(size_t)l * NPR_ + np] = (mx > 0.f) ? mx / 127.f : 0.f;
}

// MFMA input GEMM v2: fragment-linear operands, NO LDS / NO barriers.
__global__ __launch_bounds__(256) void k_gih_mfma(const ushort* __restrict__ Xq,
        const ushort* __restrict__ Wq,
        const float* __restrict__ b0, const float* __restrict__ b1,
        ushort* __restrict__ preT) {
    const int l = blockIdx.z;
    const int my = blockIdx.y;
    const float* bb = l ? b1 : b0;
    const int wid = threadIdx.x >> 6, lane = threadIdx.x & 63;
    const int nt = blockIdx.x * 4 + wid;
    const ushort* wp = Wq + (((size_t)l * NTIL_ + nt) * 1024 + lane) * 8;
    const ushort* xp = Xq + ((size_t)my * 16 * 1024 + lane) * 8;
    f32x4 acc[16];
    #pragma unroll
    for (int i = 0; i < 16; ++i) acc[i] = (f32x4){0.f, 0.f, 0.f, 0.f};
    for (int ks = 0; ks < 16; ++ks) {
        bf16x8 b = *(const bf16x8*)(wp + (size_t)ks * 512);
        #pragma unroll
        for (int i = 0; i < 16; ++i) {
            bf16x8 a = *(const bf16x8*)(xp + ((size_t)i * 16 + ks) * 512);
            acc[i] = __builtin_amdgcn_mfma_f32_16x16x32_bf16(a, b, acc[i], 0, 0, 0);
        }
    }
    const int n = nt * 16 + (lane & 15);
    const float bv = (n < G4_) ? bb[(size_t)(n & 3) * NC_ + (n >> 2)] : 0.f;
    const int r0 = (lane >> 4) * 4;
    ushort* po = preT + ((size_t)l * NPR_ + n) * 512 + my * 256;
    #pragma unroll
    for (int i = 0; i < 16; ++i) {
        ushort4 o;
        o.x = bfc(acc[i][0] + bv); o.y = bfc(acc[i][1] + bv);
        o.z = bfc(acc[i][2] + bv); o.w = bfc(acc[i][3] + bv);
        *(ushort4*)(po + i * 16 + r0) = o;
    }
}

// Fused recurrent step v8: 2 n-tiles per block (640 blocks = 2.5/CU for load depth),
// single-plane int8 h, native i8 MFMA (K=64); grid (NTIL_/2, 1, 2), 256 threads.
__global__ __launch_bounds__(256, 4) void k_step(const signed char* __restrict__ Wq8,
        const float* __restrict__ sW, const ushort* __restrict__ preT,
        const signed char* __restrict__ h_in, signed char* __restrict__ h_out,
        float* __restrict__ cst, float* __restrict__ hbuf,
        const float* __restrict__ scal_ih, const float* __restrict__ scal_hh,
        int t) {
    const int l = blockIdx.z;
    const int nt0 = blockIdx.x * 2;
    const int tid = threadIdx.x;
    const int w = tid >> 6, lane = tid & 63;
    // gate operand prefetch (threads 0..127: item = tid>>6, unit jq, batch b)
    float pv[4], swv[4];
    const int item_g = tid >> 6;
    const int b_g = tid & 15, jq_g = (tid >> 4) & 3;
    const int nt_g = nt0 + item_g;
    const int jc_g = nt_g * 4 + jq_g;
    if (tid < 128) {
        #pragma unroll
        for (int q = 0; q < 4; ++q) {
            const int row = nt_g * 16 + jq_g * 4 + q;
            pv[q]  = b2f(preT[((size_t)l * NPR_ + row) * 512 + t * 16 + b_g]);
            swv[q] = sW[(size_t)l * NPR_ + row] * (1.f / 127.f);
        }
    }
    const signed char* wbase = Wq8 + (((size_t)l * NTIL_ + nt0) * 40 + w * 10) * 1024 + lane * 16;
    const signed char* hbase = h_in + (size_t)l * 40960 + (w * 10) * 1024 + lane * 16;
    i32x4 s0 = {0, 0, 0, 0}, s1 = {0, 0, 0, 0};
    #pragma unroll 5
    for (int ks = 0; ks < 10; ++ks) {
        i32x4 ah = *(const i32x4*)(hbase + ks * 1024);
        i32x4 b0 = *(const i32x4*)(wbase + ks * 1024);
        i32x4 b1 = *(const i32x4*)(wbase + 40960 + ks * 1024);
        s0 = __builtin_amdgcn_mfma_i32_16x16x64_i8(ah, b0, s0, 0, 0, 0);
        s1 = __builtin_amdgcn_mfma_i32_16x16x64_i8(ah, b1, s1, 0, 0, 0);
    }
    __shared__ float gl[2][4][16][17];   // [item][wave][nlocal][b]
    const int col = lane & 15;
    const int m0 = (lane >> 4) * 4;
    #pragma unroll
    for (int v = 0; v < 4; ++v) {
        gl[0][w][col][m0 + v] = (float)s0[v];
        gl[1][w][col][m0 + v] = (float)s1[v];
    }
    __syncthreads();
    // gate pass: threads 0..127, one (item, unit, batch) each
    if (tid < 128 && jc_g < NC_) {
        float g[4];
        #pragma unroll
        for (int q = 0; q < 4; ++q) {
            float s = gl[item_g][0][jq_g * 4 + q][b_g] + gl[item_g][1][jq_g * 4 + q][b_g]
                    + gl[item_g][2][jq_g * 4 + q][b_g] + gl[item_g][3][jq_g * 4 + q][b_g];
            g[q] = s * swv[q] + pv[q];
        }
        float* cp = cst + ((size_t)l * NC_ + jc_g) * B_ + b_g;
        float ci = *cp;
        float cn = sigf(g[1]) * ci + sigf(g[0]) * tanhf(g[2]);
        float hn = sigf(g[3]) * tanhf(cn);
        *cp = cn;
        const int ks = jc_g >> 6, kgrp = (jc_g >> 4) & 3, e = jc_g & 15;
        h_out[(size_t)l * 40960 + (size_t)ks * 1024 + (kgrp * 16 + b_g) * 16 + e] =
            (signed char)(int)rintf(hn * 127.f);
        float sc = (l ? scal_hh : scal_ih)[jc_g];
        hbuf[(((size_t)l * T_ + t) * B_ + b_g) * NC_ + jc_g] = hn * sc;
    }
}

// Merged: Bt[k][h] = idct_hid[h][k]  and  AinT[g][j] = idct_in[j][g]
__global__ void k_btat(const float* __restrict__ Bh, float* __restrict__ Bt,
                       const float* __restrict__ Ain, float* __restrict__ AinT) {
    int idx = blockIdx.x * 256 + threadIdx.x;
    if (idx < NR_ * H_) {
        int k = idx / H_, h = idx - k * H_;
        Bt[idx] = Bh[(size_t)h * H_ + k];
        AinT[idx] = Ain[(size_t)h * I_ + k];
    }
}

// yih[t,b,h] = sum_k Bt[k,h]*v[k]; u via 8-lane groups + coalesced AinT rows
__global__ __launch_bounds__(576) void k_yih(const float* __restrict__ x,
        const float* __restrict__ AinT, const float* __restrict__ Bt,
        const float* __restrict__ hbuf0, float* __restrict__ yih) {
    __shared__ __align__(16) float xl[I_];
    __shared__ float u[NR_ + 1];
    __shared__ __align__(16) float v[NR_ + 1];
    const int tb = blockIdx.x, tid = threadIdx.x;
    for (int i = tid; i < I_; i += 576) xl[i] = x[(size_t)tb * I_ + i];
    if (tid == 0) { u[NR_] = 0.f; v[NR_] = 0.f; }
    const int g = tid >> 3, lane = tid & 7;
    __syncthreads();
    if (g < NR_) {
        const float* ap = AinT + (size_t)g * I_ + lane * 4;
        const float* hp = xl + lane * 4;
        float a = 0.f;
        #pragma unroll
        for (int m = 0; m < 16; ++m) {
            float4 aq = *(const float4*)(ap + m * 32);
            float4 hq = *(const float4*)(hp + m * 32);
            a += aq.x * hq.x + aq.y * hq.y + aq.z * hq.z + aq.w * hq.w;
        }
        a += __shfl_xor(a, 1); a += __shfl_xor(a, 2); a += __shfl_xor(a, 4);
        if (lane == 0) u[g] = a;
    }
    __syncthreads();
    if (g < NR_) {
        int start = g * NR_ - (g * (g - 1)) / 2;
        int cnt = NR_ - g;
        const float* cf = hbuf0 + (size_t)tb * NC_ + start;
        float a = 0.f;
        for (int m = lane; m < cnt; m += 8) a += cf[m] * u[cnt - 1 - m];
        a += __shfl_xor(a, 1); a += __shfl_xor(a, 2); a += __shfl_xor(a, 4);
        if (lane == 0) v[g] = a;
    }
    __syncthreads();
    if (tid < H_) {
        float4 vv[18];
        #pragma unroll
        for (int q = 0; q < 18; ++q) vv[q] = *(const float4*)(v + q * 4);
        float a0 = 0.f, a1 = 0.f;
        #pragma unroll
        for (int k = 0; k < NR_; ++k) {
            float vk = ((const float*)vv)[k];
            ((k & 1) ? a1 : a0) += Bt[(size_t)k * H_ + tid] * vk;
        }
        yih[(size_t)tb * H_ + tid] = a0 + a1;
    }
}

// sequential phase-2 v7: 1024 threads; h-phase split 2 threads/hid (36/35 MACs);
// Bt in LDS pitch 520; dbuf hl; yv prefetch; u-phase unchanged (no reg arrays).
#define BTP_ 520
__global__ __launch_bounds__(1024) void k_seq(const float* __restrict__ yih,
        const float* __restrict__ Bt, const float* __restrict__ cf_all,
        const float* __restrict__ bias, float* __restrict__ out) {
    __shared__ __align__(16) float bt[NR_ * BTP_];   // 147.7 KB
    __shared__ __align__(16) float hl[2][H_];
    __shared__ float u[NR_ + 1];
    __shared__ __align__(16) float v[NR_ + 9];       // padded so half*36 float4 reads stay in-bounds
    const int b = blockIdx.x, tid = threadIdx.x;
    for (int i = tid; i < NR_ * H_; i += 1024)
        bt[(i >> 9) * BTP_ + (i & 511)] = Bt[i];
    for (int i = tid; i < H_; i += 1024) hl[0][i] = 0.f;
    if (tid < 9) { u[NR_] = 0.f; v[NR_ + tid] = 0.f; }
    const int hid = tid >> 1, half = tid & 1;        // h-phase ids
    const int kbase = half * 36, kn = 36 - half;     // 36 or 35 k's
    const float bv = bias[hid];
    const int g = tid >> 3, lane = tid & 7;          // u/v-phase ids (g<71 active)
    int start = 0, cnt = 0;
    if (g < NR_) { start = g * NR_ - (g * (g - 1)) / 2; cnt = NR_ - g; }
    int p = 0;
    __syncthreads();
    for (int t = 0; t < T_; ++t) {
        // prefetch global operands (hidden under u-phase)
        float yv = 0.f;
        if (half == 0) yv = yih[((size_t)t * B_ + b) * H_ + hid];
        float cfv[9];
        if (g < NR_) {
            const float* cf = cf_all + ((size_t)t * B_ + b) * NC_ + start;
            #pragma unroll
            for (int mi = 0; mi < 9; ++mi) {
                int m = mi * 8 + lane;
                cfv[mi] = cf[m < cnt ? m : (cnt - 1)];
            }
        }
        // u[g] = sum_j bt[g][j]*h[j] (8-lane groups, single accumulator)
        if (g < NR_) {
            const float* bp = bt + g * BTP_ + lane * 4;
            const float* hp = hl[p] + lane * 4;
            float a = 0.f;
            #pragma unroll
            for (int m = 0; m < 16; ++m) {
                float4 bq = *(const float4*)(bp + m * 32);
                float4 hq = *(const float4*)(hp + m * 32);
                a += bq.x * hq.x + bq.y * hq.y + bq.z * hq.z + bq.w * hq.w;
            }
            a += __shfl_xor(a, 1); a += __shfl_xor(a, 2); a += __shfl_xor(a, 4);
            if (lane == 0) u[g] = a;
        }
        __syncthreads();
        // v[g] = triangular combine with prefetched coeffs
        if (g < NR_) {
            float a = 0.f;
            #pragma unroll
            for (int mi = 0; mi < 9; ++mi) {
                int m = mi * 8 + lane;
                a += (m < cnt) ? cfv[mi] * u[cnt - 1 - m] : 0.f;
            }
            a += __shfl_xor(a, 1); a += __shfl_xor(a, 2); a += __shfl_xor(a, 4);
            if (lane == 0) v[g] = a;
        }
        __syncthreads();
        // h-phase: 2 threads per hid, halves of k-range, shfl combine
        {
            float4 vv[9];
            #pragma unroll
            for (int q = 0; q < 9; ++q) vv[q] = *(const float4*)(v + kbase + q * 4);
            const float* vf = (const float*)vv;
            float a0 = 0.f, a1 = 0.f;
            #pragma unroll
            for (int k = 0; k < 34; k += 2) {
                a0 += bt[(kbase + k) * BTP_ + hid] * vf[k];
                a1 += bt[(kbase + k + 1) * BTP_ + hid] * vf[k + 1];
            }
            a0 += bt[(kbase + 34) * BTP_ + hid] * vf[34];
            if (kn == 36) a1 += bt[(kbase + 35) * BTP_ + hid] * vf[35];
            float a = a0 + a1;
            a += __shfl_xor(a, 1);
            if (half == 0) {
                float hv = tanhf(yv + a + bv);
                out[((size_t)t * B_ + b) * H_ + hid] = hv;
                hl[p ^ 1][hid] = hv;
            }
        }
        __syncthreads();
        p ^= 1;
    }
}

extern "C" void kernel_launch(void* const* d_in, const int* in_sizes, int n_in,
                              void* d_out, int out_size, void* d_ws, size_t ws_size,
                              hipStream_t stream) {
    const float* x        = (const float*)d_in[0];
    const float* wih_ih   = (const float*)d_in[1];
    const float* wih_hh   = (const float*)d_in[2];
    const float* wih_b    = (const float*)d_in[3];
    const float* whh_ih   = (const float*)d_in[4];
    const float* whh_hh   = (const float*)d_in[5];
    const float* whh_b    = (const float*)d_in[6];
    const float* scal_ih  = (const float*)d_in[7];
    const float* scal_hh  = (const float*)d_in[8];
    const float* bias     = (const float*)d_in[9];
    const float* idct_in  = (const float*)d_in[10];
    const float* idct_hid = (const float*)d_in[11];
    float* out = (float*)d_out;

    const size_t WP8_B  = (size_t)2 * NPR_ * NCP_;        //  52,428,800 (int8, K64-interleaved)
    const size_t SW_B   = (size_t)2 * NPR_ * 4;           //      81,920
    const size_t PRET_B = (size_t)2 * NPR_ * 512 * 2;     //  20,971,520
    const size_t HBUF_B = (size_t)2 * T_ * B_ * NC_ * 4;  //  10,469,376
    const size_t HBF_B  = (size_t)2 * 2 * 40960;          //     163,840 (pp x layer, hi only)
    const size_t CST_B  = (size_t)2 * NC_ * B_ * 4;       //     327,168
    const size_t YIH_B  = (size_t)T_ * B_ * H_ * 4;
    const size_t BT_B   = (size_t)NR_ * H_ * 4;
    const size_t AT_B   = (size_t)NR_ * I_ * 4;
    const size_t need = WP8_B + SW_B + PRET_B + HBUF_B + HBF_B + CST_B + YIH_B + BT_B + AT_B + 4096;

    char* ws = (char*)d_ws;
    size_t off = 0;
    auto alloc = [&](size_t bytes) -> void* {
        void* p = (void*)(ws + off);
        off += (bytes + 255) & ~(size_t)255;
        return p;
    };

    if (ws_size < need) return;   // harness workspace has always been >160MB

    signed char* Wp8 = (signed char*)alloc(WP8_B);
    float*  sW   = (float*)alloc(SW_B);
    ushort* preT = (ushort*)alloc(PRET_B);
    float*  hbuf = (float*)alloc(HBUF_B);
    signed char* hbf = (signed char*)alloc(HBF_B);
    float*  cst  = (float*)alloc(CST_B);
    float*  yih  = (float*)alloc(YIH_B);
    float*  Bt   = (float*)alloc(BT_B);
    float*  AinT = (float*)alloc(AT_B);
    // aliases inside Wp8 region (dead before k_cvt_whh_i8 runs)
    ushort* Wq   = (ushort*)Wp8;                       // 21.0 MB frag-linear Wih
    ushort* Xq   = (ushort*)((char*)Wp8 + 21000192);   // +0.5 MB, < 52.4 MB

    {   // zero hbf (both pp buffers) + cst (contiguous allocs)
        int n = (int)((HBF_B + CST_B) / 4);
        hipLaunchKernelGGL(k_zero, dim3((n + 255) / 256), dim3(256), 0, stream,
                           (float*)hbf, n);
    }
    hipLaunchKernelGGL(k_cvt_xq, dim3(128), dim3(256), 0, stream, x, Xq);
    hipLaunchKernelGGL(k_cvt_w512q, dim3(2560, 1, 2), dim3(256), 0, stream,
                       wih_ih, whh_ih, Wq);
    hipLaunchKernelGGL(k_gih_mfma, dim3(160, 2, 2), dim3(256), 0, stream,
                       Xq, Wq, wih_b, whh_b, preT);
    hipLaunchKernelGGL(k_cvt_whh_i8, dim3(NPR_ / 4, 1, 2), dim3(256), 0, stream,
                       wih_hh, whh_hh, Wp8, sW);

    const size_t HS = (size_t)2 * 40960;   // bytes per ping-pong buffer (2 layers, hi)
    for (int t = 0; t < T_; ++t) {
        const signed char* hin  = hbf + (size_t)(t & 1) * HS;
        signed char*       hout = hbf + (size_t)((t & 1) ^ 1) * HS;
        hipLaunchKernelGGL(k_step, dim3(NTIL_ / 2, 1, 2), dim3(256), 0, stream,
                           Wp8, sW, preT, hin, hout, cst, hbuf, scal_ih, scal_hh, t);
    }

    hipLaunchKernelGGL(k_btat, dim3((NR_ * H_ + 255) / 256), dim3(256), 0, stream,
                       idct_hid, Bt, idct_in, AinT);
    hipLaunchKernelGGL(k_yih, dim3(T_ * B_), dim3(576), 0, stream,
                       x, AinT, Bt, hbuf, yih);
    hipLaunchKernelGGL(k_seq, dim3(B_), dim3(1024), 0, stream,
                       yih, Bt, hbuf + (size_t)T_ * B_ * NC_, bias, out);
}

// Round 21
// 559.940 us; speedup vs baseline: 1.0059x; 1.0059x over previous
//
#include <hip/hip_runtime.h>
#include <hip/hip_bf16.h>

#define T_ 32
#define B_ 16
#define I_ 512
#define H_ 512
#define OFF_ 441
#define NR_ 71           // I_ - OFF_
#define NC_ 2556         // NR_*(NR_+1)/2
#define G4_ (4*NC_)      // 10224
#define NCP_ 2560        // K padded
#define NPR_ 10240       // padded gate-permuted row count
#define NTIL_ 640        // NPR_/16

typedef __attribute__((ext_vector_type(8))) short bf16x8;
typedef __attribute__((ext_vector_type(4))) float f32x4;
typedef __attribute__((ext_vector_type(4))) int   i32x4;

__device__ __forceinline__ ushort bfc(float f) {
    __hip_bfloat16 h = __float2bfloat16(f);
    return *(ushort*)&h;
}
__device__ __forceinline__ float b2f(ushort u) {
    return __uint_as_float((uint)u << 16);
}
__device__ __forceinline__ float sigf(float x) { return 1.f / (1.f + expf(-x)); }

__global__ void k_zero(float* __restrict__ p, int n) {
    int i = blockIdx.x * 256 + threadIdx.x;
    if (i < n) p[i] = 0.f;
}

// x fp32 [512][512] -> bf16 MFMA-fragment layout Xq[mt][ks][lane][8]
__global__ void k_cvt_xq(const float* __restrict__ x, ushort* __restrict__ Xq) {
    int tid = blockIdx.x * 256 + threadIdx.x;    // 0..32767
    int mt = tid >> 10, rem = tid & 1023;
    int ks = rem >> 6, lane = rem & 63;
    int row = lane & 15, kq = lane >> 4;
    const float* src = x + ((size_t)(mt * 16 + row)) * I_ + ks * 32 + kq * 8;
    float4 v0 = *(const float4*)(src);
    float4 v1 = *(const float4*)(src + 4);
    union { bf16x8 v; ushort us[8]; } o;
    o.us[0] = bfc(v0.x); o.us[1] = bfc(v0.y); o.us[2] = bfc(v0.z); o.us[3] = bfc(v0.w);
    o.us[4] = bfc(v1.x); o.us[5] = bfc(v1.y); o.us[6] = bfc(v1.z); o.us[7] = bfc(v1.w);
    *(bf16x8*)(Xq + (size_t)tid * 8) = o.v;
}

// Wih[l] fp32 [G4][512] -> bf16 gate-permuted MFMA-fragment layout
__global__ void k_cvt_w512q(const float* __restrict__ W0, const float* __restrict__ W1,
                            ushort* __restrict__ dst) {
    const int l = blockIdx.z;
    const float* src = l ? W1 : W0;
    int tid = blockIdx.x * 256 + threadIdx.x;    // 0..655359 per layer
    int nt = tid >> 10, rem = tid & 1023;
    int ks = rem >> 6, lane = rem & 63;
    int row = lane & 15, kq = lane >> 4;
    int np = nt * 16 + row;
    int jc = np >> 2, q = np & 3;
    union { bf16x8 v; ushort us[8]; } o;
    if (jc < NC_) {
        const float* sp = src + ((size_t)q * NC_ + jc) * I_ + ks * 32 + kq * 8;
        float4 v0 = *(const float4*)(sp);
        float4 v1 = *(const float4*)(sp + 4);
        o.us[0] = bfc(v0.x); o.us[1] = bfc(v0.y); o.us[2] = bfc(v0.z); o.us[3] = bfc(v0.w);
        o.us[4] = bfc(v1.x); o.us[5] = bfc(v1.y); o.us[6] = bfc(v1.z); o.us[7] = bfc(v1.w);
    } else {
        #pragma unroll
        for (int e = 0; e < 8; ++e) o.us[e] = 0;
    }
    *(bf16x8*)(dst + ((size_t)l * NTIL_ * 1024 + tid) * 8) = o.v;
}

// Whh[l] fp32 [G4][2556] -> int8, K=64-interleaved i8-MFMA fragment layout.
__global__ __launch_bounds__(256) void k_cvt_whh_i8(const float* __restrict__ W0,
        const float* __restrict__ W1,
        signed char* __restrict__ dst, float* __restrict__ sW) {
    const int l = blockIdx.z;
    const float* src = l ? W1 : W0;
    const int np = blockIdx.x * 4 + (threadIdx.x >> 6);
    const int lane = threadIdx.x & 63;
    const int jc = np >> 2, q = np & 3;
    float w[40];
    float mx = 0.f;
    if (jc < NC_) {
        const float* row = src + ((size_t)q * NC_ + jc) * NC_;
        #pragma unroll
        for (int g = 0; g < 5; ++g) {
            int k0 = g * 512 + lane * 8;
            #pragma unroll
            for (int e = 0; e < 8; ++e) {
                int k = k0 + e;
                float v = (k < NC_) ? row[k] : 0.f;
                w[g * 8 + e] = v;
                mx = fmaxf(mx, fabsf(v));
            }
        }
    } else {
        #pragma unroll
        for (int i = 0; i < 40; ++i) w[i] = 0.f;
    }
    #pragma unroll
    for (int d = 1; d < 64; d <<= 1) mx = fmaxf(mx, __shfl_xor(mx, d));
    const float inv = (mx > 0.f) ? 127.f / mx : 0.f;
    const int nt = np >> 4, r = np & 15;
    signed char* obase = dst + (((size_t)l * NTIL_ + nt) * 40) * 1024;
    #pragma unroll
    for (int g = 0; g < 5; ++g) {
        int k0 = g * 512 + lane * 8;
        int ks = k0 >> 6, kgrp = (k0 >> 4) & 3, e = k0 & 15;   // e in {0,8}
        uint lo = 0, hi = 0;
        #pragma unroll
        for (int ee = 0; ee < 4; ++ee) {
            lo |= ((uint)(uchar)(signed char)(int)rintf(w[g * 8 + ee] * inv)) << (8 * ee);
            hi |= ((uint)(uchar)(signed char)(int)rintf(w[g * 8 + 4 + ee] * inv)) << (8 * ee);
        }
        *(uint2*)(obase + (size_t)ks * 1024 + (kgrp * 16 + r) * 16 + e) = make_uint2(lo, hi);
    }
    if (lane == 0) sW[(size_t)l * NPR_ + np] = (mx > 0.f) ? mx / 127.f : 0.f;
}

// MFMA input GEMM v2: fragment-linear operands, NO LDS / NO barriers.
__global__ __launch_bounds__(256) void k_gih_mfma(const ushort* __restrict__ Xq,
        const ushort* __restrict__ Wq,
        const float* __restrict__ b0, const float* __restrict__ b1,
        ushort* __restrict__ preT) {
    const int l = blockIdx.z;
    const int my = blockIdx.y;
    const float* bb = l ? b1 : b0;
    const int wid = threadIdx.x >> 6, lane = threadIdx.x & 63;
    const int nt = blockIdx.x * 4 + wid;
    const ushort* wp = Wq + (((size_t)l * NTIL_ + nt) * 1024 + lane) * 8;
    const ushort* xp = Xq + ((size_t)my * 16 * 1024 + lane) * 8;
    f32x4 acc[16];
    #pragma unroll
    for (int i = 0; i < 16; ++i) acc[i] = (f32x4){0.f, 0.f, 0.f, 0.f};
    for (int ks = 0; ks < 16; ++ks) {
        bf16x8 b = *(const bf16x8*)(wp + (size_t)ks * 512);
        #pragma unroll
        for (int i = 0; i < 16; ++i) {
            bf16x8 a = *(const bf16x8*)(xp + ((size_t)i * 16 + ks) * 512);
            acc[i] = __builtin_amdgcn_mfma_f32_16x16x32_bf16(a, b, acc[i], 0, 0, 0);
        }
    }
    const int n = nt * 16 + (lane & 15);
    const float bv = (n < G4_) ? bb[(size_t)(n & 3) * NC_ + (n >> 2)] : 0.f;
    const int r0 = (lane >> 4) * 4;
    ushort* po = preT + ((size_t)l * NPR_ + n) * 512 + my * 256;
    #pragma unroll
    for (int i = 0; i < 16; ++i) {
        ushort4 o;
        o.x = bfc(acc[i][0] + bv); o.y = bfc(acc[i][1] + bv);
        o.z = bfc(acc[i][2] + bv); o.w = bfc(acc[i][3] + bv);
        *(ushort4*)(po + i * 16 + r0) = o;
    }
}

// Fused recurrent step v8: 2 n-tiles per block (640 blocks = 2.5/CU for load depth),
// single-plane int8 h, native i8 MFMA (K=64); grid (NTIL_/2, 1, 2), 256 threads.
__global__ __launch_bounds__(256, 4) void k_step(const signed char* __restrict__ Wq8,
        const float* __restrict__ sW, const ushort* __restrict__ preT,
        const signed char* __restrict__ h_in, signed char* __restrict__ h_out,
        float* __restrict__ cst, float* __restrict__ hbuf,
        const float* __restrict__ scal_ih, const float* __restrict__ scal_hh,
        int t) {
    const int l = blockIdx.z;
    const int nt0 = blockIdx.x * 2;
    const int tid = threadIdx.x;
    const int w = tid >> 6, lane = tid & 63;
    // gate operand prefetch (threads 0..127: item = tid>>6, unit jq, batch b)
    float pv[4], swv[4];
    const int item_g = tid >> 6;
    const int b_g = tid & 15, jq_g = (tid >> 4) & 3;
    const int nt_g = nt0 + item_g;
    const int jc_g = nt_g * 4 + jq_g;
    if (tid < 128) {
        #pragma unroll
        for (int q = 0; q < 4; ++q) {
            const int row = nt_g * 16 + jq_g * 4 + q;
            pv[q]  = b2f(preT[((size_t)l * NPR_ + row) * 512 + t * 16 + b_g]);
            swv[q] = sW[(size_t)l * NPR_ + row] * (1.f / 127.f);
        }
    }
    const signed char* wbase = Wq8 + (((size_t)l * NTIL_ + nt0) * 40 + w * 10) * 1024 + lane * 16;
    const signed char* hbase = h_in + (size_t)l * 40960 + (w * 10) * 1024 + lane * 16;
    i32x4 s0 = {0, 0, 0, 0}, s1 = {0, 0, 0, 0};
    #pragma unroll 5
    for (int ks = 0; ks < 10; ++ks) {
        i32x4 ah = *(const i32x4*)(hbase + ks * 1024);
        i32x4 b0 = *(const i32x4*)(wbase + ks * 1024);
        i32x4 b1 = *(const i32x4*)(wbase + 40960 + ks * 1024);
        s0 = __builtin_amdgcn_mfma_i32_16x16x64_i8(ah, b0, s0, 0, 0, 0);
        s1 = __builtin_amdgcn_mfma_i32_16x16x64_i8(ah, b1, s1, 0, 0, 0);
    }
    __shared__ float gl[2][4][16][17];   // [item][wave][nlocal][b]
    const int col = lane & 15;
    const int m0 = (lane >> 4) * 4;
    #pragma unroll
    for (int v = 0; v < 4; ++v) {
        gl[0][w][col][m0 + v] = (float)s0[v];
        gl[1][w][col][m0 + v] = (float)s1[v];
    }
    __syncthreads();
    // gate pass: threads 0..127, one (item, unit, batch) each
    if (tid < 128 && jc_g < NC_) {
        float g[4];
        #pragma unroll
        for (int q = 0; q < 4; ++q) {
            float s = gl[item_g][0][jq_g * 4 + q][b_g] + gl[item_g][1][jq_g * 4 + q][b_g]
                    + gl[item_g][2][jq_g * 4 + q][b_g] + gl[item_g][3][jq_g * 4 + q][b_g];
            g[q] = s * swv[q] + pv[q];
        }
        float* cp = cst + ((size_t)l * NC_ + jc_g) * B_ + b_g;
        float ci = *cp;
        float cn = sigf(g[1]) * ci + sigf(g[0]) * tanhf(g[2]);
        float hn = sigf(g[3]) * tanhf(cn);
        *cp = cn;
        const int ks = jc_g >> 6, kgrp = (jc_g >> 4) & 3, e = jc_g & 15;
        h_out[(size_t)l * 40960 + (size_t)ks * 1024 + (kgrp * 16 + b_g) * 16 + e] =
            (signed char)(int)rintf(hn * 127.f);
        float sc = (l ? scal_hh : scal_ih)[jc_g];
        hbuf[(((size_t)l * T_ + t) * B_ + b_g) * NC_ + jc_g] = hn * sc;
    }
}

// Merged: Bt[k][h] = idct_hid[h][k]  and  AinT[g][j] = idct_in[j][g]
__global__ void k_btat(const float* __restrict__ Bh, float* __restrict__ Bt,
                       const float* __restrict__ Ain, float* __restrict__ AinT) {
    int idx = blockIdx.x * 256 + threadIdx.x;
    if (idx < NR_ * H_) {
        int k = idx / H_, h = idx - k * H_;
        Bt[idx] = Bh[(size_t)h * H_ + k];
        AinT[idx] = Ain[(size_t)h * I_ + k];
    }
}

// yih[t,b,h] = sum_k Bt[k,h]*v[k]; u via 8-lane groups + coalesced AinT rows
__global__ __launch_bounds__(576) void k_yih(const float* __restrict__ x,
        const float* __restrict__ AinT, const float* __restrict__ Bt,
        const float* __restrict__ hbuf0, float* __restrict__ yih) {
    __shared__ __align__(16) float xl[I_];
    __shared__ float u[NR_ + 1];
    __shared__ __align__(16) float v[NR_ + 1];
    const int tb = blockIdx.x, tid = threadIdx.x;
    for (int i = tid; i < I_; i += 576) xl[i] = x[(size_t)tb * I_ + i];
    if (tid == 0) { u[NR_] = 0.f; v[NR_] = 0.f; }
    const int g = tid >> 3, lane = tid & 7;
    __syncthreads();
    if (g < NR_) {
        const float* ap = AinT + (size_t)g * I_ + lane * 4;
        const float* hp = xl + lane * 4;
        float a = 0.f;
        #pragma unroll
        for (int m = 0; m < 16; ++m) {
            float4 aq = *(const float4*)(ap + m * 32);
            float4 hq = *(const float4*)(hp + m * 32);
            a += aq.x * hq.x + aq.y * hq.y + aq.z * hq.z + aq.w * hq.w;
        }
        a += __shfl_xor(a, 1); a += __shfl_xor(a, 2); a += __shfl_xor(a, 4);
        if (lane == 0) u[g] = a;
    }
    __syncthreads();
    if (g < NR_) {
        int start = g * NR_ - (g * (g - 1)) / 2;
        int cnt = NR_ - g;
        const float* cf = hbuf0 + (size_t)tb * NC_ + start;
        float a = 0.f;
        for (int m = lane; m < cnt; m += 8) a += cf[m] * u[cnt - 1 - m];
        a += __shfl_xor(a, 1); a += __shfl_xor(a, 2); a += __shfl_xor(a, 4);
        if (lane == 0) v[g] = a;
    }
    __syncthreads();
    if (tid < H_) {
        float4 vv[18];
        #pragma unroll
        for (int q = 0; q < 18; ++q) vv[q] = *(const float4*)(v + q * 4);
        float a0 = 0.f, a1 = 0.f;
        #pragma unroll
        for (int k = 0; k < NR_; ++k) {
            float vk = ((const float*)vv)[k];
            ((k & 1) ? a1 : a0) += Bt[(size_t)k * H_ + tid] * vk;
        }
        yih[(size_t)tb * H_ + tid] = a0 + a1;
    }
}

// sequential phase-2 (round-19 verified, ~104 us): 576 threads; Bt in LDS pitch 520;
// dbuf hl (3 barriers); yv prefetch; single-accumulator u-phase (NO reg arrays).
#define BTP_ 520
__global__ __launch_bounds__(576) void k_seq(const float* __restrict__ yih,
        const float* __restrict__ Bt, const float* __restrict__ cf_all,
        const float* __restrict__ bias, float* __restrict__ out) {
    __shared__ __align__(16) float bt[NR_ * BTP_];   // 147.7 KB
    __shared__ __align__(16) float hl[2][H_];
    __shared__ float u[NR_ + 1];
    __shared__ __align__(16) float v[NR_ + 1];
    const int b = blockIdx.x, tid = threadIdx.x;
    for (int i = tid; i < NR_ * H_; i += 576)
        bt[(i >> 9) * BTP_ + (i & 511)] = Bt[i];
    for (int i = tid; i < H_; i += 576) hl[0][i] = 0.f;
    if (tid == 0) { u[NR_] = 0.f; v[NR_] = 0.f; }
    const float bv = (tid < H_) ? bias[tid] : 0.f;
    const int g = tid >> 3, lane = tid & 7;
    int start = 0, cnt = 0;
    if (g < NR_) { start = g * NR_ - (g * (g - 1)) / 2; cnt = NR_ - g; }
    int p = 0;
    __syncthreads();
    for (int t = 0; t < T_; ++t) {
        float yv = 0.f;
        if (tid < H_) yv = yih[((size_t)t * B_ + b) * H_ + tid];
        float cfv[9];
        if (g < NR_) {
            const float* cf = cf_all + ((size_t)t * B_ + b) * NC_ + start;
            #pragma unroll
            for (int mi = 0; mi < 9; ++mi) {
                int m = mi * 8 + lane;
                cfv[mi] = cf[m < cnt ? m : (cnt - 1)];
            }
        }
        if (g < NR_) {
            const float* bp = bt + g * BTP_ + lane * 4;
            const float* hp = hl[p] + lane * 4;
            float a = 0.f;
            #pragma unroll
            for (int m = 0; m < 16; ++m) {
                float4 bq = *(const float4*)(bp + m * 32);
                float4 hq = *(const float4*)(hp + m * 32);
                a += bq.x * hq.x + bq.y * hq.y + bq.z * hq.z + bq.w * hq.w;
            }
            a += __shfl_xor(a, 1); a += __shfl_xor(a, 2); a += __shfl_xor(a, 4);
            if (lane == 0) u[g] = a;
        }
        __syncthreads();
        if (g < NR_) {
            float a = 0.f;
            #pragma unroll
            for (int mi = 0; mi < 9; ++mi) {
                int m = mi * 8 + lane;
                a += (m < cnt) ? cfv[mi] * u[cnt - 1 - m] : 0.f;
            }
            a += __shfl_xor(a, 1); a += __shfl_xor(a, 2); a += __shfl_xor(a, 4);
            if (lane == 0) v[g] = a;
        }
        __syncthreads();
        if (tid < H_) {
            float4 vv[18];
            #pragma unroll
            for (int q = 0; q < 18; ++q) vv[q] = *(const float4*)(v + q * 4);
            float a0 = 0.f, a1 = 0.f;
            #pragma unroll
            for (int k = 0; k < NR_; ++k) {
                float vk = ((const float*)vv)[k];
                ((k & 1) ? a1 : a0) += bt[k * BTP_ + tid] * vk;
            }
            float hv = tanhf(yv + a0 + a1 + bv);
            out[((size_t)t * B_ + b) * H_ + tid] = hv;
            hl[p ^ 1][tid] = hv;
        }
        __syncthreads();
        p ^= 1;
    }
}

extern "C" void kernel_launch(void* const* d_in, const int* in_sizes, int n_in,
                              void* d_out, int out_size, void* d_ws, size_t ws_size,
                              hipStream_t stream) {
    const float* x        = (const float*)d_in[0];
    const float* wih_ih   = (const float*)d_in[1];
    const float* wih_hh   = (const float*)d_in[2];
    const float* wih_b    = (const float*)d_in[3];
    const float* whh_ih   = (const float*)d_in[4];
    const float* whh_hh   = (const float*)d_in[5];
    const float* whh_b    = (const float*)d_in[6];
    const float* scal_ih  = (const float*)d_in[7];
    const float* scal_hh  = (const float*)d_in[8];
    const float* bias     = (const float*)d_in[9];
    const float* idct_in  = (const float*)d_in[10];
    const float* idct_hid = (const float*)d_in[11];
    float* out = (float*)d_out;

    const size_t WP8_B  = (size_t)2 * NPR_ * NCP_;        //  52,428,800 (int8, K64-interleaved)
    const size_t SW_B   = (size_t)2 * NPR_ * 4;           //      81,920
    const size_t PRET_B = (size_t)2 * NPR_ * 512 * 2;     //  20,971,520
    const size_t HBUF_B = (size_t)2 * T_ * B_ * NC_ * 4;  //  10,469,376
    const size_t HBF_B  = (size_t)2 * 2 * 40960;          //     163,840 (pp x layer, hi only)
    const size_t CST_B  = (size_t)2 * NC_ * B_ * 4;       //     327,168
    const size_t YIH_B  = (size_t)T_ * B_ * H_ * 4;
    const size_t BT_B   = (size_t)NR_ * H_ * 4;
    const size_t AT_B   = (size_t)NR_ * I_ * 4;
    const size_t need = WP8_B + SW_B + PRET_B + HBUF_B + HBF_B + CST_B + YIH_B + BT_B + AT_B + 4096;

    char* ws = (char*)d_ws;
    size_t off = 0;
    auto alloc = [&](size_t bytes) -> void* {
        void* p = (void*)(ws + off);
        off += (bytes + 255) & ~(size_t)255;
        return p;
    };

    if (ws_size < need) return;   // harness workspace has always been >160MB

    signed char* Wp8 = (signed char*)alloc(WP8_B);
    float*  sW   = (float*)alloc(SW_B);
    ushort* preT = (ushort*)alloc(PRET_B);
    float*  hbuf = (float*)alloc(HBUF_B);
    signed char* hbf = (signed char*)alloc(HBF_B);
    float*  cst  = (float*)alloc(CST_B);
    float*  yih  = (float*)alloc(YIH_B);
    float*  Bt   = (float*)alloc(BT_B);
    float*  AinT = (float*)alloc(AT_B);
    // aliases inside Wp8 region (dead before k_cvt_whh_i8 runs)
    ushort* Wq   = (ushort*)Wp8;                       // 21.0 MB frag-linear Wih
    ushort* Xq   = (ushort*)((char*)Wp8 + 21000192);   // +0.5 MB, < 52.4 MB

    {   // zero hbf (both pp buffers) + cst (contiguous allocs)
        int n = (int)((HBF_B + CST_B) / 4);
        hipLaunchKernelGGL(k_zero, dim3((n + 255) / 256), dim3(256), 0, stream,
                           (float*)hbf, n);
    }
    hipLaunchKernelGGL(k_cvt_xq, dim3(128), dim3(256), 0, stream, x, Xq);
    hipLaunchKernelGGL(k_cvt_w512q, dim3(2560, 1, 2), dim3(256), 0, stream,
                       wih_ih, whh_ih, Wq);
    hipLaunchKernelGGL(k_gih_mfma, dim3(160, 2, 2), dim3(256), 0, stream,
                       Xq, Wq, wih_b, whh_b, preT);
    hipLaunchKernelGGL(k_cvt_whh_i8, dim3(NPR_ / 4, 1, 2), dim3(256), 0, stream,
                       wih_hh, whh_hh, Wp8, sW);

    const size_t HS = (size_t)2 * 40960;   // bytes per ping-pong buffer (2 layers, hi)
    for (int t = 0; t < T_; ++t) {
        const signed char* hin  = hbf + (size_t)(t & 1) * HS;
        signed char*       hout = hbf + (size_t)((t & 1) ^ 1) * HS;
        hipLaunchKernelGGL(k_step, dim3(NTIL_ / 2, 1, 2), dim3(256), 0, stream,
                           Wp8, sW, preT, hin, hout, cst, hbuf, scal_ih, scal_hh, t);
    }

    hipLaunchKernelGGL(k_btat, dim3((NR_ * H_ + 255) / 256), dim3(256), 0, stream,
                       idct_hid, Bt, idct_in, AinT);
    hipLaunchKernelGGL(k_yih, dim3(T_ * B_), dim3(576), 0, stream,
                       x, AinT, Bt, hbuf, yih);
    hipLaunchKernelGGL(k_seq, dim3(B_), dim3(576), 0, stream,
                       yih, Bt, hbuf + (size_t)T_ * B_ * NC_, bias, out);
}